// Round 3
// baseline (262.416 us; speedup 1.0000x reference)
//
#include <hip/hip_runtime.h>
#include <hip/hip_fp8.h>
#include <math.h>

typedef _Float16 f16x4 __attribute__((ext_vector_type(4)));
typedef _Float16 f16x8 __attribute__((ext_vector_type(8)));
typedef float f32x4 __attribute__((ext_vector_type(4)));
typedef __fp16 hf8 __attribute__((ext_vector_type(8)));

#define DIM 128
#define LDST 136      // padded LDS row stride in f16 elems (272B, 16B-aligned)
#define KVREC 384     // packed KV record: k fp8 [128B] | v f16 [256B]

#if defined(__has_builtin)
#if __has_builtin(__builtin_amdgcn_cvt_pk_fp8_f32) && __has_builtin(__builtin_amdgcn_cvt_pk_f32_fp8)
#define HAVE_FP8CVT 1
#endif
#endif

// pack 4 floats -> 4 fp8 e4m3 bytes in a uint
__device__ __forceinline__ unsigned int pack_fp8x4(float f0, float f1, float f2, float f3) {
#ifdef HAVE_FP8CVT
    int w = __builtin_amdgcn_cvt_pk_fp8_f32(f0, f1, 0, false);
    w = __builtin_amdgcn_cvt_pk_fp8_f32(f2, f3, w, true);
    return (unsigned int)w;
#else
    __hip_fp8_e4m3 a(f0), b(f1), c(f2), d(f3);
    return (unsigned int)a.__x | ((unsigned int)b.__x << 8) |
           ((unsigned int)c.__x << 16) | ((unsigned int)d.__x << 24);
#endif
}

// unpack 4 fp8 e4m3 bytes, accumulate dot with 4 floats of q
__device__ __forceinline__ void dot_fp8x4(float& d, unsigned int w, const float* qv) {
#ifdef HAVE_FP8CVT
    auto lo = __builtin_amdgcn_cvt_pk_f32_fp8((int)w, false);
    auto hi = __builtin_amdgcn_cvt_pk_f32_fp8((int)w, true);
    d += lo[0] * qv[0] + lo[1] * qv[1] + hi[0] * qv[2] + hi[1] * qv[3];
#else
    for (int j = 0; j < 4; ++j) {
        __hip_fp8_e4m3 t; t.__x = (unsigned char)((w >> (8 * j)) & 0xff);
        d += (float)t * qv[j];
    }
#endif
}

// ---------------------------------------------------------------------------
// Kernel 1: setup — fused weight transpose/f16-convert + CSR row_ptr build.
// blocks [0,192): transpose Wq/Wk/Wv -> f16 Wt.  blocks [192,...): row_ptr.
// ---------------------------------------------------------------------------
__global__ __launch_bounds__(256) void setup_kernel(
    const float* __restrict__ Wq, const float* __restrict__ Wk,
    const float* __restrict__ Wv, _Float16* __restrict__ Wt,
    const int* __restrict__ rows, int* __restrict__ row_ptr, int n, int e)
{
    int b = blockIdx.x;
    if (b < 192) {
        int mat = b >> 6;
        const float* W = (mat == 0) ? Wq : (mat == 1) ? Wk : Wv;
        _Float16* dst = Wt + (size_t)mat * DIM * DIM;
        int idx = (b & 63) * 256 + threadIdx.x;
        int k = idx >> 7;
        int c = idx & 127;
        dst[c * DIM + k] = (_Float16)W[idx];
    } else {
        int r = (b - 192) * 256 + threadIdx.x;
        if (r > n) return;
        if (r == n) { row_ptr[n] = e; return; }
        int lo = 0, hi = e;
        while (lo < hi) {
            int mid = (lo + hi) >> 1;
            if (rows[mid] < r) lo = mid + 1; else hi = mid;
        }
        row_ptr[r] = lo;
    }
}

// ---------------------------------------------------------------------------
// Kernel 2: fused projection GEMM  Y = gelu(X @ W + b).
// grid.y==0: query -> qf (f16).
// grid.y==1: memory staged ONCE -> both K (fp8, packed kv.k) and V (f16,
//            packed kv.v) — saves a full 25.6MB re-read of memory vs the
//            3-way split.
// ---------------------------------------------------------------------------
__global__ __launch_bounds__(256, 2) void proj_gemm_kernel(
    const float* __restrict__ query, const float* __restrict__ memory,
    const _Float16* __restrict__ Wt,
    const float* __restrict__ bq, const float* __restrict__ bk,
    const float* __restrict__ bv,
    _Float16* __restrict__ qf, unsigned char* __restrict__ kv,
    int n, int m)
{
    __shared__ _Float16 xs[128 * LDST];   // 34816 B

    int which = blockIdx.y;               // 0: query, 1: memory
    const float* X = (which == 0) ? query : memory;
    int R          = (which == 0) ? n : m;

    int tid = threadIdx.x;
    int rowblock = blockIdx.x * 128;
    if (rowblock >= R) return;

    // stage 128x128 f32 tile -> f16 LDS (coalesced float4 loads)
    for (int it = 0; it < 16; ++it) {
        int flat = it * 256 + tid;
        int r  = flat >> 5;
        int c4 = (flat & 31) * 4;
        int gr = rowblock + r;
        if (gr >= R) gr = R - 1;
        float4 x = *(const float4*)(X + (size_t)gr * DIM + c4);
        f16x4 w4;
        w4[0] = (_Float16)x.x; w4[1] = (_Float16)x.y;
        w4[2] = (_Float16)x.z; w4[3] = (_Float16)x.w;
        *(f16x4*)(&xs[r * LDST + c4]) = w4;
    }
    __syncthreads();

    int wave = tid >> 6;
    int lane = tid & 63;
    int quad = lane >> 4;
    int l16  = lane & 15;
    int wrow = wave * 32;

    // A fragments live in registers across both projections
    f16x8 afrag[2][4];
    for (int rt = 0; rt < 2; ++rt)
        for (int ks = 0; ks < 4; ++ks)
            afrag[rt][ks] = *(const f16x8*)(&xs[(wrow + rt * 16 + l16) * LDST + quad * 8 + ks * 32]);

    int nproj = (which == 0) ? 1 : 2;
    for (int p = 0; p < nproj; ++p) {
        int widx = (which == 0) ? 0 : (p == 0 ? 1 : 2);
        const _Float16* Wm = Wt + (size_t)widx * DIM * DIM;
        const float* bias  = (which == 0) ? bq : (p == 0 ? bk : bv);

        f32x4 acc[8][2];
        for (int ct = 0; ct < 8; ++ct) { acc[ct][0] = {0,0,0,0}; acc[ct][1] = {0,0,0,0}; }
        for (int ct = 0; ct < 8; ++ct) {
            const _Float16* wp = Wm + (size_t)(ct * 16 + l16) * DIM + quad * 8;
            for (int ks = 0; ks < 4; ++ks) {
                f16x8 b = *(const f16x8*)(wp + ks * 32);
                acc[ct][0] = __builtin_amdgcn_mfma_f32_16x16x32_f16(afrag[0][ks], b, acc[ct][0], 0, 0, 0);
                acc[ct][1] = __builtin_amdgcn_mfma_f32_16x16x32_f16(afrag[1][ks], b, acc[ct][1], 0, 0, 0);
            }
        }

        __syncthreads();   // xs free (afrag in regs / prior store loop done)
        for (int ct = 0; ct < 8; ++ct) {
            float bval = bias[ct * 16 + l16];
            for (int rt = 0; rt < 2; ++rt) {
                for (int reg = 0; reg < 4; ++reg) {
                    float x = acc[ct][rt][reg] + bval;
                    float t  = 0.7978845608028654f * (x + 0.044715f * x * x * x);
                    float th = 1.0f - 2.0f / (__expf(2.0f * t) + 1.0f);
                    float g  = 0.5f * x * (1.0f + th);
                    xs[(wrow + rt * 16 + quad * 4 + reg) * LDST + ct * 16 + l16] = (_Float16)g;
                }
            }
        }
        __syncthreads();

        if (which == 0) {
            // q: plain f16 rows
            for (int it = 0; it < 8; ++it) {
                int flat = it * 256 + tid;
                int r  = flat >> 4;
                int c8 = (flat & 15) * 8;
                int gr = rowblock + r;
                if (gr < R) {
                    f16x8 vv = *(const f16x8*)(&xs[r * LDST + c8]);
                    *(f16x8*)(qf + (size_t)gr * DIM + c8) = vv;
                }
            }
        } else if (p == 0) {
            // k: fp8 into kv record bytes [0,128)
            for (int it = 0; it < 8; ++it) {
                int flat = it * 256 + tid;
                int r  = flat >> 4;
                int c8 = (flat & 15) * 8;
                int gr = rowblock + r;
                if (gr < R) {
                    f16x8 h = *(const f16x8*)(&xs[r * LDST + c8]);
                    unsigned int w0 = pack_fp8x4((float)h[0], (float)h[1], (float)h[2], (float)h[3]);
                    unsigned int w1 = pack_fp8x4((float)h[4], (float)h[5], (float)h[6], (float)h[7]);
                    *(uint2*)(kv + (size_t)gr * KVREC + c8) = make_uint2(w0, w1);
                }
            }
        } else {
            // v: f16 into kv record bytes [128,384)
            for (int it = 0; it < 8; ++it) {
                int flat = it * 256 + tid;
                int r  = flat >> 4;
                int c8 = (flat & 15) * 8;
                int gr = rowblock + r;
                if (gr < R) {
                    f16x8 vv = *(const f16x8*)(&xs[r * LDST + c8]);
                    *(f16x8*)(kv + (size_t)gr * KVREC + 128 + c8 * 2) = vv;
                }
            }
        }
    }
}

// ---------------------------------------------------------------------------
// Kernel 3: per-row edge attention. R0's lean body (2 gather groups in
// flight, VGPR ~40) + two changes:
//  - persistent grid-stride launch: exactly 2048 blocks (8/CU resident) so
//    wave residency stays ~full for the whole kernel -> more outstanding
//    misses -> higher random-gather BW (R2's deep pipeline attacked the
//    wrong axis: per-wave ILP at the cost of occupancy).
//  - packed KV record (k fp8 128B | v f16 256B): one base address per edge,
//    all 3 gathered lines in one DRAM page.
// ---------------------------------------------------------------------------
__global__ __launch_bounds__(256) void edge_attn_kernel(
    const __fp16* __restrict__ qf, const unsigned char* __restrict__ kv,
    const float* __restrict__ adj_vals, const int* __restrict__ cols,
    const int* __restrict__ row_ptr, float* __restrict__ out, int n)
{
    int lane    = threadIdx.x & 63;
    int quarter = lane >> 4;
    int l16     = lane & 15;
    int gwave   = blockIdx.x * 4 + (threadIdx.x >> 6);
    int stride  = gridDim.x * 4;

    const float scale = 0.08838834764831845f;   // 1/sqrt(128)

    for (int row = gwave; row < n; row += stride) {
        int start = row_ptr[row];
        int end   = row_ptr[row + 1];

        float qv[8];
        {
            hf8 q8 = *(const hf8*)(qf + (size_t)row * DIM + l16 * 8);
#pragma unroll
            for (int j = 0; j < 8; ++j) qv[j] = (float)q8[j];
        }

        float s_sum = 0.0f;
        float acc[8];
#pragma unroll
        for (int j = 0; j < 8; ++j) acc[j] = 0.0f;

        for (int g = start; g < end; g += 8) {
            int eA = g + quarter;
            int eB = g + 4 + quarter;
            bool vA = eA < end;
            bool vB = eB < end;
            int last = end - 1;
            int iA = vA ? eA : last;
            int iB = vB ? eB : last;
            int   cA = cols[iA];
            int   cB = cols[iB];
            float aA = adj_vals[iA] * scale;
            float aB = adj_vals[iB] * scale;

            const unsigned char* baseA = kv + (size_t)cA * KVREC;
            const unsigned char* baseB = kv + (size_t)cB * KVREC;
            uint2 rA  = *(const uint2*)(baseA + l16 * 8);
            uint2 rB  = *(const uint2*)(baseB + l16 * 8);
            hf8   vA8 = *(const hf8*)(baseA + 128 + l16 * 16);
            hf8   vB8 = *(const hf8*)(baseB + 128 + l16 * 16);

            float dA = 0.0f, dB = 0.0f;
            dot_fp8x4(dA, rA.x, qv);
            dot_fp8x4(dA, rA.y, qv + 4);
            dot_fp8x4(dB, rB.x, qv);
            dot_fp8x4(dB, rB.y, qv + 4);
            dA += __shfl_xor(dA, 1); dB += __shfl_xor(dB, 1);
            dA += __shfl_xor(dA, 2); dB += __shfl_xor(dB, 2);
            dA += __shfl_xor(dA, 4); dB += __shfl_xor(dB, 4);
            dA += __shfl_xor(dA, 8); dB += __shfl_xor(dB, 8);

            float pA_ = vA ? __expf(dA * aA) : 0.0f;
            float pB_ = vB ? __expf(dB * aB) : 0.0f;
            s_sum += pA_ + pB_;
#pragma unroll
            for (int j = 0; j < 8; ++j)
                acc[j] += pA_ * (float)vA8[j] + pB_ * (float)vB8[j];
        }

        // merge the 4 quarter groups
        s_sum += __shfl_xor(s_sum, 16);
        s_sum += __shfl_xor(s_sum, 32);
#pragma unroll
        for (int j = 0; j < 8; ++j) {
            acc[j] += __shfl_xor(acc[j], 16);
            acc[j] += __shfl_xor(acc[j], 32);
        }
        float inv = (s_sum > 0.0f) ? 1.0f / s_sum : 0.0f;   // empty row -> zeros

        if (quarter == 0) {
            float4* dst = (float4*)(out + (size_t)row * DIM + l16 * 8);
            dst[0] = make_float4(acc[0] * inv, acc[1] * inv, acc[2] * inv, acc[3] * inv);
            dst[1] = make_float4(acc[4] * inv, acc[5] * inv, acc[6] * inv, acc[7] * inv);
        }
    }
}

// ---------------------------------------------------------------------------
extern "C" void kernel_launch(void* const* d_in, const int* in_sizes, int n_in,
                              void* d_out, int out_size, void* d_ws, size_t ws_size,
                              hipStream_t stream)
{
    const float* query    = (const float*)d_in[0];
    const float* memory   = (const float*)d_in[1];
    const float* adj_vals = (const float*)d_in[2];
    const float* Wq       = (const float*)d_in[3];
    const float* bq       = (const float*)d_in[4];
    const float* Wk       = (const float*)d_in[5];
    const float* bk       = (const float*)d_in[6];
    const float* Wv       = (const float*)d_in[7];
    const float* bv       = (const float*)d_in[8];
    const int*   rows     = (const int*)d_in[9];
    const int*   cols     = (const int*)d_in[10];
    float* out = (float*)d_out;

    int n = in_sizes[0] / DIM;   // 50000
    int m = in_sizes[1] / DIM;   // 50000
    int e = in_sizes[9];         // 1600000

    // workspace layout (16B-aligned)
    char* ws = (char*)d_ws;
    size_t off = 0;
    _Float16* Wt  = (_Float16*)(ws + off); off += (size_t)3 * DIM * DIM * 2;   // 98304
    _Float16* qf  = (_Float16*)(ws + off); off += (size_t)n * DIM * 2;         // 12.8MB
    unsigned char* kv = (unsigned char*)(ws + off); off += (size_t)m * KVREC;  // 19.2MB packed
    int* row_ptr  = (int*)(ws + off);      off += (size_t)(n + 1) * 4;

    int rp_blocks = (n + 1 + 255) / 256;
    setup_kernel<<<dim3(192 + rp_blocks), 256, 0, stream>>>(
        Wq, Wk, Wv, Wt, rows, row_ptr, n, e);

    int mx = (n > m) ? n : m;
    proj_gemm_kernel<<<dim3((mx + 127) / 128, 2), 256, 0, stream>>>(
        query, memory, Wt, bq, bk, bv, qf, kv, n, m);

    edge_attn_kernel<<<dim3(2048), 256, 0, stream>>>(
        (const __fp16*)qf, kv, adj_vals, cols, row_ptr, out, n);
}

// Round 4
// 235.435 us; speedup vs baseline: 1.1146x; 1.1146x over previous
//
#include <hip/hip_runtime.h>
#include <hip/hip_fp8.h>
#include <math.h>

typedef _Float16 f16x4 __attribute__((ext_vector_type(4)));
typedef _Float16 f16x8 __attribute__((ext_vector_type(8)));
typedef float f32x4 __attribute__((ext_vector_type(4)));
typedef __fp16 hf8 __attribute__((ext_vector_type(8)));

#define DIM 128
#define LDST 136   // padded LDS row stride in f16 elems (272B, 16B-aligned)

#if defined(__has_builtin)
#if __has_builtin(__builtin_amdgcn_cvt_pk_fp8_f32) && __has_builtin(__builtin_amdgcn_cvt_pk_f32_fp8)
#define HAVE_FP8CVT 1
#endif
#endif

// pack 4 floats -> 4 fp8 e4m3 bytes in a uint
__device__ __forceinline__ unsigned int pack_fp8x4(float f0, float f1, float f2, float f3) {
#ifdef HAVE_FP8CVT
    int w = __builtin_amdgcn_cvt_pk_fp8_f32(f0, f1, 0, false);
    w = __builtin_amdgcn_cvt_pk_fp8_f32(f2, f3, w, true);
    return (unsigned int)w;
#else
    __hip_fp8_e4m3 a(f0), b(f1), c(f2), d(f3);
    return (unsigned int)a.__x | ((unsigned int)b.__x << 8) |
           ((unsigned int)c.__x << 16) | ((unsigned int)d.__x << 24);
#endif
}

// unpack 4 fp8 e4m3 bytes, accumulate dot with 4 floats of q
__device__ __forceinline__ void dot_fp8x4(float& d, unsigned int w, const float* qv) {
#ifdef HAVE_FP8CVT
    auto lo = __builtin_amdgcn_cvt_pk_f32_fp8((int)w, false);
    auto hi = __builtin_amdgcn_cvt_pk_f32_fp8((int)w, true);
    d += lo[0] * qv[0] + lo[1] * qv[1] + hi[0] * qv[2] + hi[1] * qv[3];
#else
    for (int j = 0; j < 4; ++j) {
        __hip_fp8_e4m3 t; t.__x = (unsigned char)((w >> (8 * j)) & 0xff);
        d += (float)t * qv[j];
    }
#endif
}

// ---------------------------------------------------------------------------
// Kernel 1: setup — fused weight transpose/f16-convert + CSR row_ptr build.
// blocks [0,192): transpose Wq/Wk/Wv -> f16 Wt.  blocks [192,...): row_ptr.
// ---------------------------------------------------------------------------
__global__ __launch_bounds__(256) void setup_kernel(
    const float* __restrict__ Wq, const float* __restrict__ Wk,
    const float* __restrict__ Wv, _Float16* __restrict__ Wt,
    const int* __restrict__ rows, int* __restrict__ row_ptr, int n, int e)
{
    int b = blockIdx.x;
    if (b < 192) {
        int mat = b >> 6;
        const float* W = (mat == 0) ? Wq : (mat == 1) ? Wk : Wv;
        _Float16* dst = Wt + (size_t)mat * DIM * DIM;
        int idx = (b & 63) * 256 + threadIdx.x;
        int k = idx >> 7;
        int c = idx & 127;
        dst[c * DIM + k] = (_Float16)W[idx];
    } else {
        int r = (b - 192) * 256 + threadIdx.x;
        if (r > n) return;
        if (r == n) { row_ptr[n] = e; return; }
        int lo = 0, hi = e;
        while (lo < hi) {
            int mid = (lo + hi) >> 1;
            if (rows[mid] < r) lo = mid + 1; else hi = mid;
        }
        row_ptr[r] = lo;
    }
}

// ---------------------------------------------------------------------------
// Kernel 2: fused projection GEMM  Y = gelu(X @ W + b).
// which==0 -> qf (f16), which==1 -> k8 (fp8 e4m3), which==2 -> v16 (f16).
// CHANGE this round: __launch_bounds__(256,3) -> 3 blocks/CU resident
// (was 2). The block body is hard-serial (stage->MFMA->gelu->store); more
// resident blocks overlap those phases across blocks. VGPR cap 170,
// est. usage ~140 (no spill); LDS 3x34.8KB = 104KB/CU.
// ---------------------------------------------------------------------------
__global__ __launch_bounds__(256, 3) void proj_gemm_kernel(
    const float* __restrict__ query, const float* __restrict__ memory,
    const _Float16* __restrict__ Wt,
    const float* __restrict__ bq, const float* __restrict__ bk,
    const float* __restrict__ bv,
    _Float16* __restrict__ qf, unsigned char* __restrict__ k8,
    _Float16* __restrict__ v16, int n, int m)
{
    __shared__ _Float16 xs[128 * LDST];   // 34816 B

    int which = blockIdx.y;
    const float* X     = (which == 0) ? query : memory;
    const _Float16* Wm = Wt + (size_t)which * DIM * DIM;
    const float* bias  = (which == 0) ? bq : (which == 1) ? bk : bv;
    int R              = (which == 0) ? n : m;

    int tid = threadIdx.x;
    int rowblock = blockIdx.x * 128;
    if (rowblock >= R) return;

    for (int it = 0; it < 16; ++it) {
        int flat = it * 256 + tid;
        int r  = flat >> 5;
        int c4 = (flat & 31) * 4;
        int gr = rowblock + r;
        if (gr >= R) gr = R - 1;
        float4 x = *(const float4*)(X + (size_t)gr * DIM + c4);
        f16x4 w4;
        w4[0] = (_Float16)x.x; w4[1] = (_Float16)x.y;
        w4[2] = (_Float16)x.z; w4[3] = (_Float16)x.w;
        *(f16x4*)(&xs[r * LDST + c4]) = w4;
    }
    __syncthreads();

    int wave = tid >> 6;
    int lane = tid & 63;
    int quad = lane >> 4;
    int l16  = lane & 15;
    int wrow = wave * 32;

    f16x8 afrag[2][4];
    for (int rt = 0; rt < 2; ++rt)
        for (int ks = 0; ks < 4; ++ks)
            afrag[rt][ks] = *(const f16x8*)(&xs[(wrow + rt * 16 + l16) * LDST + quad * 8 + ks * 32]);

    f32x4 acc[8][2];
    for (int ct = 0; ct < 8; ++ct) { acc[ct][0] = {0,0,0,0}; acc[ct][1] = {0,0,0,0}; }
    for (int ct = 0; ct < 8; ++ct) {
        const _Float16* wp = Wm + (size_t)(ct * 16 + l16) * DIM + quad * 8;
        for (int ks = 0; ks < 4; ++ks) {
            f16x8 b = *(const f16x8*)(wp + ks * 32);
            acc[ct][0] = __builtin_amdgcn_mfma_f32_16x16x32_f16(afrag[0][ks], b, acc[ct][0], 0, 0, 0);
            acc[ct][1] = __builtin_amdgcn_mfma_f32_16x16x32_f16(afrag[1][ks], b, acc[ct][1], 0, 0, 0);
        }
    }

    __syncthreads();
    for (int ct = 0; ct < 8; ++ct) {
        float bval = bias[ct * 16 + l16];
        for (int rt = 0; rt < 2; ++rt) {
            for (int reg = 0; reg < 4; ++reg) {
                float x = acc[ct][rt][reg] + bval;
                float t  = 0.7978845608028654f * (x + 0.044715f * x * x * x);
                float th = 1.0f - 2.0f / (__expf(2.0f * t) + 1.0f);
                float g  = 0.5f * x * (1.0f + th);
                xs[(wrow + rt * 16 + quad * 4 + reg) * LDST + ct * 16 + l16] = (_Float16)g;
            }
        }
    }
    __syncthreads();

    if (which == 1) {
        // fp8 e4m3 output: 8 f16 -> 8 bytes per chunk, coalesced 8B stores
        for (int it = 0; it < 8; ++it) {
            int flat = it * 256 + tid;
            int r  = flat >> 4;
            int c8 = (flat & 15) * 8;
            int gr = rowblock + r;
            if (gr < R) {
                f16x8 h = *(const f16x8*)(&xs[r * LDST + c8]);
                unsigned int w0 = pack_fp8x4((float)h[0], (float)h[1], (float)h[2], (float)h[3]);
                unsigned int w1 = pack_fp8x4((float)h[4], (float)h[5], (float)h[6], (float)h[7]);
                *(uint2*)(k8 + (size_t)gr * DIM + c8) = make_uint2(w0, w1);
            }
        }
    } else {
        _Float16* Ybase = (which == 0) ? qf : v16;
        for (int it = 0; it < 8; ++it) {
            int flat = it * 256 + tid;
            int r  = flat >> 4;
            int c8 = (flat & 15) * 8;
            int gr = rowblock + r;
            if (gr < R) {
                f16x8 vv = *(const f16x8*)(&xs[r * LDST + c8]);
                *(f16x8*)(Ybase + (size_t)gr * DIM + c8) = vv;
            }
        }
    }
}

// ---------------------------------------------------------------------------
// Kernel 3: per-row edge attention — EXACT revert to the R0 body (proven
// 84.3us / 258MB / 3.44TB/s). Four structural variants (f16-k, 4-slot
// pipeline, persistent grid, packed KV) all measured at or below its
// ~57G granules/s service rate; this body is the empirical optimum.
// ---------------------------------------------------------------------------
__global__ __launch_bounds__(256) void edge_attn_kernel(
    const __fp16* __restrict__ qf, const unsigned char* __restrict__ k8,
    const __fp16* __restrict__ v16, const float* __restrict__ adj_vals,
    const int* __restrict__ cols, const int* __restrict__ row_ptr,
    float* __restrict__ out, int n)
{
    int row = blockIdx.x * 4 + (threadIdx.x >> 6);
    if (row >= n) return;
    int lane    = threadIdx.x & 63;
    int quarter = lane >> 4;
    int l16     = lane & 15;

    int start = row_ptr[row];
    int end   = row_ptr[row + 1];

    float qv[8];
    {
        hf8 q8 = *(const hf8*)(qf + (size_t)row * DIM + l16 * 8);
#pragma unroll
        for (int j = 0; j < 8; ++j) qv[j] = (float)q8[j];
    }

    float s_sum = 0.0f;
    float acc[8];
#pragma unroll
    for (int j = 0; j < 8; ++j) acc[j] = 0.0f;

    const float scale = 0.08838834764831845f;   // 1/sqrt(128)

    for (int g = start; g < end; g += 8) {
        int eA = g + quarter;
        int eB = g + 4 + quarter;
        bool vA = eA < end;
        bool vB = eB < end;
        int last = end - 1;
        int iA = vA ? eA : last;
        int iB = vB ? eB : last;
        int   cA = cols[iA];
        int   cB = cols[iB];
        float aA = adj_vals[iA] * scale;
        float aB = adj_vals[iB] * scale;

        uint2 rA = *(const uint2*)(k8 + (size_t)cA * DIM + l16 * 8);
        uint2 rB = *(const uint2*)(k8 + (size_t)cB * DIM + l16 * 8);
        hf8 vA8 = *(const hf8*)(v16 + (size_t)cA * DIM + l16 * 8);
        hf8 vB8 = *(const hf8*)(v16 + (size_t)cB * DIM + l16 * 8);

        float dA = 0.0f, dB = 0.0f;
        dot_fp8x4(dA, rA.x, qv);
        dot_fp8x4(dA, rA.y, qv + 4);
        dot_fp8x4(dB, rB.x, qv);
        dot_fp8x4(dB, rB.y, qv + 4);
        dA += __shfl_xor(dA, 1); dB += __shfl_xor(dB, 1);
        dA += __shfl_xor(dA, 2); dB += __shfl_xor(dB, 2);
        dA += __shfl_xor(dA, 4); dB += __shfl_xor(dB, 4);
        dA += __shfl_xor(dA, 8); dB += __shfl_xor(dB, 8);

        float pA_ = vA ? __expf(dA * aA) : 0.0f;
        float pB_ = vB ? __expf(dB * aB) : 0.0f;
        s_sum += pA_ + pB_;
#pragma unroll
        for (int j = 0; j < 8; ++j)
            acc[j] += pA_ * (float)vA8[j] + pB_ * (float)vB8[j];
    }

    // merge the 4 quarter groups
    s_sum += __shfl_xor(s_sum, 16);
    s_sum += __shfl_xor(s_sum, 32);
#pragma unroll
    for (int j = 0; j < 8; ++j) {
        acc[j] += __shfl_xor(acc[j], 16);
        acc[j] += __shfl_xor(acc[j], 32);
    }
    float inv = (s_sum > 0.0f) ? 1.0f / s_sum : 0.0f;   // empty row -> zeros

    if (quarter == 0) {
        float4* dst = (float4*)(out + (size_t)row * DIM + l16 * 8);
        dst[0] = make_float4(acc[0] * inv, acc[1] * inv, acc[2] * inv, acc[3] * inv);
        dst[1] = make_float4(acc[4] * inv, acc[5] * inv, acc[6] * inv, acc[7] * inv);
    }
}

// ---------------------------------------------------------------------------
extern "C" void kernel_launch(void* const* d_in, const int* in_sizes, int n_in,
                              void* d_out, int out_size, void* d_ws, size_t ws_size,
                              hipStream_t stream)
{
    const float* query    = (const float*)d_in[0];
    const float* memory   = (const float*)d_in[1];
    const float* adj_vals = (const float*)d_in[2];
    const float* Wq       = (const float*)d_in[3];
    const float* bq       = (const float*)d_in[4];
    const float* Wk       = (const float*)d_in[5];
    const float* bk       = (const float*)d_in[6];
    const float* Wv       = (const float*)d_in[7];
    const float* bv       = (const float*)d_in[8];
    const int*   rows     = (const int*)d_in[9];
    const int*   cols     = (const int*)d_in[10];
    float* out = (float*)d_out;

    int n = in_sizes[0] / DIM;   // 50000
    int m = in_sizes[1] / DIM;   // 50000
    int e = in_sizes[9];         // 1600000

    // workspace layout (16B-aligned)
    char* ws = (char*)d_ws;
    size_t off = 0;
    _Float16* Wt  = (_Float16*)(ws + off); off += (size_t)3 * DIM * DIM * 2;   // 98304
    _Float16* qf  = (_Float16*)(ws + off); off += (size_t)n * DIM * 2;         // 12.8MB
    _Float16* v16 = (_Float16*)(ws + off); off += (size_t)m * DIM * 2;         // 12.8MB
    unsigned char* k8 = (unsigned char*)(ws + off); off += (size_t)m * DIM;    // 6.4MB
    int* row_ptr  = (int*)(ws + off);      off += (size_t)(n + 1) * 4;

    int rp_blocks = (n + 1 + 255) / 256;
    setup_kernel<<<dim3(192 + rp_blocks), 256, 0, stream>>>(
        Wq, Wk, Wv, Wt, rows, row_ptr, n, e);

    proj_gemm_kernel<<<dim3((n + 127) / 128, 3), 256, 0, stream>>>(
        query, memory, Wt, bq, bk, bv, qf, k8, v16, n, m);

    edge_attn_kernel<<<dim3((n + 3) / 4), 256, 0, stream>>>(
        (const __fp16*)qf, k8, (const __fp16*)v16, adj_vals, cols, row_ptr, out, n);
}

// Round 5
// 231.394 us; speedup vs baseline: 1.1341x; 1.0175x over previous
//
#include <hip/hip_runtime.h>
#include <hip/hip_fp8.h>
#include <math.h>

typedef _Float16 f16x4 __attribute__((ext_vector_type(4)));
typedef _Float16 f16x8 __attribute__((ext_vector_type(8)));
typedef float f32x4 __attribute__((ext_vector_type(4)));
typedef __fp16 hf8 __attribute__((ext_vector_type(8)));

#define DIM 128
#define LDST 136   // padded LDS row stride in f16 elems (272B, 16B-aligned)

#if defined(__has_builtin)
#if __has_builtin(__builtin_amdgcn_cvt_pk_fp8_f32) && __has_builtin(__builtin_amdgcn_cvt_pk_f32_fp8)
#define HAVE_FP8CVT 1
#endif
#endif

// pack 4 floats -> 4 fp8 e4m3 bytes in a uint
__device__ __forceinline__ unsigned int pack_fp8x4(float f0, float f1, float f2, float f3) {
#ifdef HAVE_FP8CVT
    int w = __builtin_amdgcn_cvt_pk_fp8_f32(f0, f1, 0, false);
    w = __builtin_amdgcn_cvt_pk_fp8_f32(f2, f3, w, true);
    return (unsigned int)w;
#else
    __hip_fp8_e4m3 a(f0), b(f1), c(f2), d(f3);
    return (unsigned int)a.__x | ((unsigned int)b.__x << 8) |
           ((unsigned int)c.__x << 16) | ((unsigned int)d.__x << 24);
#endif
}

// unpack 4 fp8 e4m3 bytes, accumulate dot with 4 floats of q
__device__ __forceinline__ void dot_fp8x4(float& d, unsigned int w, const float* qv) {
#ifdef HAVE_FP8CVT
    auto lo = __builtin_amdgcn_cvt_pk_f32_fp8((int)w, false);
    auto hi = __builtin_amdgcn_cvt_pk_f32_fp8((int)w, true);
    d += lo[0] * qv[0] + lo[1] * qv[1] + hi[0] * qv[2] + hi[1] * qv[3];
#else
    for (int j = 0; j < 4; ++j) {
        __hip_fp8_e4m3 t; t.__x = (unsigned char)((w >> (8 * j)) & 0xff);
        d += (float)t * qv[j];
    }
#endif
}

// extract signed int8 byte j from word, as float (v_bfe_i32 + v_cvt_f32_i32)
__device__ __forceinline__ float i8f(unsigned int w, int j) {
    return (float)((signed char)((w >> (8 * j)) & 0xff));
}

// ---------------------------------------------------------------------------
// Kernel 1: setup — fused weight transpose/f16-convert + CSR row_ptr build.
// blocks [0,192): transpose Wq/Wk/Wv -> f16 Wt.  blocks [192,...): row_ptr.
// ---------------------------------------------------------------------------
__global__ __launch_bounds__(256) void setup_kernel(
    const float* __restrict__ Wq, const float* __restrict__ Wk,
    const float* __restrict__ Wv, _Float16* __restrict__ Wt,
    const int* __restrict__ rows, int* __restrict__ row_ptr, int n, int e)
{
    int b = blockIdx.x;
    if (b < 192) {
        int mat = b >> 6;
        const float* W = (mat == 0) ? Wq : (mat == 1) ? Wk : Wv;
        _Float16* dst = Wt + (size_t)mat * DIM * DIM;
        int idx = (b & 63) * 256 + threadIdx.x;
        int k = idx >> 7;
        int c = idx & 127;
        dst[c * DIM + k] = (_Float16)W[idx];
    } else {
        int r = (b - 192) * 256 + threadIdx.x;
        if (r > n) return;
        if (r == n) { row_ptr[n] = e; return; }
        int lo = 0, hi = e;
        while (lo < hi) {
            int mid = (lo + hi) >> 1;
            if (rows[mid] < r) lo = mid + 1; else hi = mid;
        }
        row_ptr[r] = lo;
    }
}

// ---------------------------------------------------------------------------
// Kernel 2: fused projection GEMM  Y = gelu(X @ W + b).
// which==0 -> qf (f16)
// which==1 -> k8 (fp8 e4m3; proven at absmax 2^-8)
// which==2 -> v8 (int8, per-row symmetric scale in scl[]) — NEW this round:
//   per-row max|v| -> absolute quant error <= max/254 (~0.005), vs fp8's
//   relative 2^-4 (~0.06 at |v|~1). Halves v gather traffic in edge kernel.
// ---------------------------------------------------------------------------
__global__ __launch_bounds__(256, 3) void proj_gemm_kernel(
    const float* __restrict__ query, const float* __restrict__ memory,
    const _Float16* __restrict__ Wt,
    const float* __restrict__ bq, const float* __restrict__ bk,
    const float* __restrict__ bv,
    _Float16* __restrict__ qf, unsigned char* __restrict__ k8,
    unsigned char* __restrict__ v8, float* __restrict__ scl,
    int n, int m)
{
    __shared__ _Float16 xs[128 * LDST];   // 34816 B

    int which = blockIdx.y;
    const float* X     = (which == 0) ? query : memory;
    const _Float16* Wm = Wt + (size_t)which * DIM * DIM;
    const float* bias  = (which == 0) ? bq : (which == 1) ? bk : bv;
    int R              = (which == 0) ? n : m;

    int tid = threadIdx.x;
    int rowblock = blockIdx.x * 128;
    if (rowblock >= R) return;

    for (int it = 0; it < 16; ++it) {
        int flat = it * 256 + tid;
        int r  = flat >> 5;
        int c4 = (flat & 31) * 4;
        int gr = rowblock + r;
        if (gr >= R) gr = R - 1;
        float4 x = *(const float4*)(X + (size_t)gr * DIM + c4);
        f16x4 w4;
        w4[0] = (_Float16)x.x; w4[1] = (_Float16)x.y;
        w4[2] = (_Float16)x.z; w4[3] = (_Float16)x.w;
        *(f16x4*)(&xs[r * LDST + c4]) = w4;
    }
    __syncthreads();

    int wave = tid >> 6;
    int lane = tid & 63;
    int quad = lane >> 4;
    int l16  = lane & 15;
    int wrow = wave * 32;

    f16x8 afrag[2][4];
    for (int rt = 0; rt < 2; ++rt)
        for (int ks = 0; ks < 4; ++ks)
            afrag[rt][ks] = *(const f16x8*)(&xs[(wrow + rt * 16 + l16) * LDST + quad * 8 + ks * 32]);

    f32x4 acc[8][2];
    for (int ct = 0; ct < 8; ++ct) { acc[ct][0] = {0,0,0,0}; acc[ct][1] = {0,0,0,0}; }
    for (int ct = 0; ct < 8; ++ct) {
        const _Float16* wp = Wm + (size_t)(ct * 16 + l16) * DIM + quad * 8;
        for (int ks = 0; ks < 4; ++ks) {
            f16x8 b = *(const f16x8*)(wp + ks * 32);
            acc[ct][0] = __builtin_amdgcn_mfma_f32_16x16x32_f16(afrag[0][ks], b, acc[ct][0], 0, 0, 0);
            acc[ct][1] = __builtin_amdgcn_mfma_f32_16x16x32_f16(afrag[1][ks], b, acc[ct][1], 0, 0, 0);
        }
    }

    __syncthreads();
    for (int ct = 0; ct < 8; ++ct) {
        float bval = bias[ct * 16 + l16];
        for (int rt = 0; rt < 2; ++rt) {
            for (int reg = 0; reg < 4; ++reg) {
                float x = acc[ct][rt][reg] + bval;
                float t  = 0.7978845608028654f * (x + 0.044715f * x * x * x);
                float th = 1.0f - 2.0f / (__expf(2.0f * t) + 1.0f);
                float g  = 0.5f * x * (1.0f + th);
                xs[(wrow + rt * 16 + quad * 4 + reg) * LDST + ct * 16 + l16] = (_Float16)g;
            }
        }
    }
    __syncthreads();

    if (which == 0) {
        for (int it = 0; it < 8; ++it) {
            int flat = it * 256 + tid;
            int r  = flat >> 4;
            int c8 = (flat & 15) * 8;
            int gr = rowblock + r;
            if (gr < R) {
                f16x8 vv = *(const f16x8*)(&xs[r * LDST + c8]);
                *(f16x8*)(qf + (size_t)gr * DIM + c8) = vv;
            }
        }
    } else if (which == 1) {
        // k: fp8 e4m3, coalesced 8B stores
        for (int it = 0; it < 8; ++it) {
            int flat = it * 256 + tid;
            int r  = flat >> 4;
            int c8 = (flat & 15) * 8;
            int gr = rowblock + r;
            if (gr < R) {
                f16x8 h = *(const f16x8*)(&xs[r * LDST + c8]);
                unsigned int w0 = pack_fp8x4((float)h[0], (float)h[1], (float)h[2], (float)h[3]);
                unsigned int w1 = pack_fp8x4((float)h[4], (float)h[5], (float)h[6], (float)h[7]);
                *(uint2*)(k8 + (size_t)gr * DIM + c8) = make_uint2(w0, w1);
            }
        }
    } else {
        // v: int8 per-row scale. In each it, the 16-lane group (flat&15)
        // covers the FULL 128-dim row r -> row-max via 4 shfl_xor steps
        // (groups are 16-aligned within the wave).
        for (int it = 0; it < 8; ++it) {
            int flat = it * 256 + tid;
            int r  = flat >> 4;
            int c8 = (flat & 15) * 8;
            int gr = rowblock + r;
            f16x8 h = *(const f16x8*)(&xs[r * LDST + c8]);
            float f[8];
            float mx = 0.0f;
#pragma unroll
            for (int j = 0; j < 8; ++j) {
                f[j] = (float)h[j];
                mx = fmaxf(mx, fabsf(f[j]));
            }
            mx = fmaxf(mx, __shfl_xor(mx, 1));
            mx = fmaxf(mx, __shfl_xor(mx, 2));
            mx = fmaxf(mx, __shfl_xor(mx, 4));
            mx = fmaxf(mx, __shfl_xor(mx, 8));
            float qs = (mx > 0.0f) ? 127.0f / mx : 0.0f;
            if (gr < R) {
                unsigned int w0 = 0, w1 = 0;
#pragma unroll
                for (int j = 0; j < 4; ++j) {
                    int q = (int)rintf(fminf(fmaxf(f[j] * qs, -127.0f), 127.0f));
                    w0 |= ((unsigned int)(q & 0xff)) << (8 * j);
                }
#pragma unroll
                for (int j = 0; j < 4; ++j) {
                    int q = (int)rintf(fminf(fmaxf(f[4 + j] * qs, -127.0f), 127.0f));
                    w1 |= ((unsigned int)(q & 0xff)) << (8 * j);
                }
                *(uint2*)(v8 + (size_t)gr * DIM + c8) = make_uint2(w0, w1);
                if ((flat & 15) == 0)
                    scl[gr] = mx * (1.0f / 127.0f);   // dequant scale
            }
        }
    }
}

// ---------------------------------------------------------------------------
// Kernel 3: per-row edge attention — R0's proven body (84us) with ONE
// change: v gathered as int8 (1 granule) instead of f16 (2 granules).
// 3 -> 2 cache lines per edge; per-edge dequant scale folded into the
// softmax weight (ps = p * scl[col]), so inner loop is bfe+cvt+fma.
// scl[] is 200KB -> L2-resident broadcast loads.
// ---------------------------------------------------------------------------
__global__ __launch_bounds__(256) void edge_attn_kernel(
    const __fp16* __restrict__ qf, const unsigned char* __restrict__ k8,
    const unsigned char* __restrict__ v8, const float* __restrict__ scl,
    const float* __restrict__ adj_vals, const int* __restrict__ cols,
    const int* __restrict__ row_ptr, float* __restrict__ out, int n)
{
    int row = blockIdx.x * 4 + (threadIdx.x >> 6);
    if (row >= n) return;
    int lane    = threadIdx.x & 63;
    int quarter = lane >> 4;
    int l16     = lane & 15;

    int start = row_ptr[row];
    int end   = row_ptr[row + 1];

    float qv[8];
    {
        hf8 q8 = *(const hf8*)(qf + (size_t)row * DIM + l16 * 8);
#pragma unroll
        for (int j = 0; j < 8; ++j) qv[j] = (float)q8[j];
    }

    float s_sum = 0.0f;
    float acc[8];
#pragma unroll
    for (int j = 0; j < 8; ++j) acc[j] = 0.0f;

    const float scale = 0.08838834764831845f;   // 1/sqrt(128)

    for (int g = start; g < end; g += 8) {
        int eA = g + quarter;
        int eB = g + 4 + quarter;
        bool vA = eA < end;
        bool vB = eB < end;
        int last = end - 1;
        int iA = vA ? eA : last;
        int iB = vB ? eB : last;
        int   cA = cols[iA];
        int   cB = cols[iB];
        float aA = adj_vals[iA] * scale;
        float aB = adj_vals[iB] * scale;

        uint2 rA = *(const uint2*)(k8 + (size_t)cA * DIM + l16 * 8);
        uint2 rB = *(const uint2*)(k8 + (size_t)cB * DIM + l16 * 8);
        uint2 wA = *(const uint2*)(v8 + (size_t)cA * DIM + l16 * 8);
        uint2 wB = *(const uint2*)(v8 + (size_t)cB * DIM + l16 * 8);
        float sA = scl[cA];
        float sB = scl[cB];

        float dA = 0.0f, dB = 0.0f;
        dot_fp8x4(dA, rA.x, qv);
        dot_fp8x4(dA, rA.y, qv + 4);
        dot_fp8x4(dB, rB.x, qv);
        dot_fp8x4(dB, rB.y, qv + 4);
        dA += __shfl_xor(dA, 1); dB += __shfl_xor(dB, 1);
        dA += __shfl_xor(dA, 2); dB += __shfl_xor(dB, 2);
        dA += __shfl_xor(dA, 4); dB += __shfl_xor(dB, 4);
        dA += __shfl_xor(dA, 8); dB += __shfl_xor(dB, 8);

        float pA_ = vA ? __expf(dA * aA) : 0.0f;
        float pB_ = vB ? __expf(dB * aB) : 0.0f;
        s_sum += pA_ + pB_;

        float psA = pA_ * sA;   // fold dequant scale into weight
        float psB = pB_ * sB;
#pragma unroll
        for (int j = 0; j < 4; ++j) {
            acc[j]     += psA * i8f(wA.x, j) + psB * i8f(wB.x, j);
            acc[4 + j] += psA * i8f(wA.y, j) + psB * i8f(wB.y, j);
        }
    }

    // merge the 4 quarter groups
    s_sum += __shfl_xor(s_sum, 16);
    s_sum += __shfl_xor(s_sum, 32);
#pragma unroll
    for (int j = 0; j < 8; ++j) {
        acc[j] += __shfl_xor(acc[j], 16);
        acc[j] += __shfl_xor(acc[j], 32);
    }
    float inv = (s_sum > 0.0f) ? 1.0f / s_sum : 0.0f;   // empty row -> zeros

    if (quarter == 0) {
        float4* dst = (float4*)(out + (size_t)row * DIM + l16 * 8);
        dst[0] = make_float4(acc[0] * inv, acc[1] * inv, acc[2] * inv, acc[3] * inv);
        dst[1] = make_float4(acc[4] * inv, acc[5] * inv, acc[6] * inv, acc[7] * inv);
    }
}

// ---------------------------------------------------------------------------
extern "C" void kernel_launch(void* const* d_in, const int* in_sizes, int n_in,
                              void* d_out, int out_size, void* d_ws, size_t ws_size,
                              hipStream_t stream)
{
    const float* query    = (const float*)d_in[0];
    const float* memory   = (const float*)d_in[1];
    const float* adj_vals = (const float*)d_in[2];
    const float* Wq       = (const float*)d_in[3];
    const float* bq       = (const float*)d_in[4];
    const float* Wk       = (const float*)d_in[5];
    const float* bk       = (const float*)d_in[6];
    const float* Wv       = (const float*)d_in[7];
    const float* bv       = (const float*)d_in[8];
    const int*   rows     = (const int*)d_in[9];
    const int*   cols     = (const int*)d_in[10];
    float* out = (float*)d_out;

    int n = in_sizes[0] / DIM;   // 50000
    int m = in_sizes[1] / DIM;   // 50000
    int e = in_sizes[9];         // 1600000

    // workspace layout (16B-aligned)
    char* ws = (char*)d_ws;
    size_t off = 0;
    _Float16* Wt  = (_Float16*)(ws + off); off += (size_t)3 * DIM * DIM * 2;   // 98304
    _Float16* qf  = (_Float16*)(ws + off); off += (size_t)n * DIM * 2;         // 12.8MB
    unsigned char* k8 = (unsigned char*)(ws + off); off += (size_t)m * DIM;    // 6.4MB
    unsigned char* v8 = (unsigned char*)(ws + off); off += (size_t)m * DIM;    // 6.4MB
    float* scl    = (float*)(ws + off);    off += (size_t)m * 4;               // 200KB
    int* row_ptr  = (int*)(ws + off);      off += (size_t)(n + 1) * 4;

    int rp_blocks = (n + 1 + 255) / 256;
    setup_kernel<<<dim3(192 + rp_blocks), 256, 0, stream>>>(
        Wq, Wk, Wv, Wt, rows, row_ptr, n, e);

    proj_gemm_kernel<<<dim3((n + 127) / 128, 3), 256, 0, stream>>>(
        query, memory, Wt, bq, bk, bv, qf, k8, v8, scl, n, m);

    edge_attn_kernel<<<dim3((n + 3) / 4), 256, 0, stream>>>(
        (const __fp16*)qf, k8, v8, scl, adj_vals, cols, row_ptr, out, n);
}

// Round 6
// 221.385 us; speedup vs baseline: 1.1853x; 1.0452x over previous
//
#include <hip/hip_runtime.h>
#include <math.h>

typedef _Float16 f16x4 __attribute__((ext_vector_type(4)));
typedef _Float16 f16x8 __attribute__((ext_vector_type(8)));
typedef float f32x4 __attribute__((ext_vector_type(4)));

#define DIM 128
#define LDST 136   // padded LDS row stride in f16 elems (272B, 16B-aligned)

#if defined(__has_builtin)
#if __has_builtin(__builtin_amdgcn_sdot4)
#define HAVE_SDOT4 1
#endif
#endif

// 4-byte int8 dot product: d += dot(a.4xi8, b.4xi8)
__device__ __forceinline__ int dot4i8(int a, int b, int c) {
#ifdef HAVE_SDOT4
    return __builtin_amdgcn_sdot4(a, b, c, false);
#else
    int s = c;
#pragma unroll
    for (int j = 0; j < 4; ++j)
        s += (int)((signed char)((a >> (8 * j)) & 0xff)) *
             (int)((signed char)((b >> (8 * j)) & 0xff));
    return s;
#endif
}

// extract signed int8 byte j from word, as float (v_bfe_i32 + v_cvt_f32_i32)
__device__ __forceinline__ float i8f(unsigned int w, int j) {
    return (float)((signed char)((w >> (8 * j)) & 0xff));
}

// ---------------------------------------------------------------------------
// Kernel 1: setup — fused weight transpose/f16-convert + CSR row_ptr build.
// blocks [0,192): transpose Wq/Wk/Wv -> f16 Wt.  blocks [192,...): row_ptr.
// ---------------------------------------------------------------------------
__global__ __launch_bounds__(256) void setup_kernel(
    const float* __restrict__ Wq, const float* __restrict__ Wk,
    const float* __restrict__ Wv, _Float16* __restrict__ Wt,
    const int* __restrict__ rows, int* __restrict__ row_ptr, int n, int e)
{
    int b = blockIdx.x;
    if (b < 192) {
        int mat = b >> 6;
        const float* W = (mat == 0) ? Wq : (mat == 1) ? Wk : Wv;
        _Float16* dst = Wt + (size_t)mat * DIM * DIM;
        int idx = (b & 63) * 256 + threadIdx.x;
        int k = idx >> 7;
        int c = idx & 127;
        dst[c * DIM + k] = (_Float16)W[idx];
    } else {
        int r = (b - 192) * 256 + threadIdx.x;
        if (r > n) return;
        if (r == n) { row_ptr[n] = e; return; }
        int lo = 0, hi = e;
        while (lo < hi) {
            int mid = (lo + hi) >> 1;
            if (rows[mid] < r) lo = mid + 1; else hi = mid;
        }
        row_ptr[r] = lo;
    }
}

// ---------------------------------------------------------------------------
// Kernel 2: fused projection GEMM  Y = gelu(X @ W + b).
// All outputs int8 with per-row symmetric scale (abs err <= rowmax/254):
//   which==0 -> q8i + sclq
//   which==1 -> k8i + scl2[].x
//   which==2 -> v8i + scl2[].y
// int8 everywhere enables v_dot4_i32_i8 on the score path in the edge
// kernel and keeps edge gather traffic at 2 cache lines/edge.
// ---------------------------------------------------------------------------
__global__ __launch_bounds__(256, 3) void proj_gemm_kernel(
    const float* __restrict__ query, const float* __restrict__ memory,
    const _Float16* __restrict__ Wt,
    const float* __restrict__ bq, const float* __restrict__ bk,
    const float* __restrict__ bv,
    unsigned char* __restrict__ q8i, float* __restrict__ sclq,
    unsigned char* __restrict__ k8i, unsigned char* __restrict__ v8i,
    float2* __restrict__ scl2, int n, int m)
{
    __shared__ _Float16 xs[128 * LDST];   // 34816 B

    int which = blockIdx.y;
    const float* X     = (which == 0) ? query : memory;
    const _Float16* Wm = Wt + (size_t)which * DIM * DIM;
    const float* bias  = (which == 0) ? bq : (which == 1) ? bk : bv;
    int R              = (which == 0) ? n : m;

    int tid = threadIdx.x;
    int rowblock = blockIdx.x * 128;
    if (rowblock >= R) return;

    for (int it = 0; it < 16; ++it) {
        int flat = it * 256 + tid;
        int r  = flat >> 5;
        int c4 = (flat & 31) * 4;
        int gr = rowblock + r;
        if (gr >= R) gr = R - 1;
        float4 x = *(const float4*)(X + (size_t)gr * DIM + c4);
        f16x4 w4;
        w4[0] = (_Float16)x.x; w4[1] = (_Float16)x.y;
        w4[2] = (_Float16)x.z; w4[3] = (_Float16)x.w;
        *(f16x4*)(&xs[r * LDST + c4]) = w4;
    }
    __syncthreads();

    int wave = tid >> 6;
    int lane = tid & 63;
    int quad = lane >> 4;
    int l16  = lane & 15;
    int wrow = wave * 32;

    f16x8 afrag[2][4];
    for (int rt = 0; rt < 2; ++rt)
        for (int ks = 0; ks < 4; ++ks)
            afrag[rt][ks] = *(const f16x8*)(&xs[(wrow + rt * 16 + l16) * LDST + quad * 8 + ks * 32]);

    f32x4 acc[8][2];
    for (int ct = 0; ct < 8; ++ct) { acc[ct][0] = {0,0,0,0}; acc[ct][1] = {0,0,0,0}; }
    for (int ct = 0; ct < 8; ++ct) {
        const _Float16* wp = Wm + (size_t)(ct * 16 + l16) * DIM + quad * 8;
        for (int ks = 0; ks < 4; ++ks) {
            f16x8 b = *(const f16x8*)(wp + ks * 32);
            acc[ct][0] = __builtin_amdgcn_mfma_f32_16x16x32_f16(afrag[0][ks], b, acc[ct][0], 0, 0, 0);
            acc[ct][1] = __builtin_amdgcn_mfma_f32_16x16x32_f16(afrag[1][ks], b, acc[ct][1], 0, 0, 0);
        }
    }

    __syncthreads();
    for (int ct = 0; ct < 8; ++ct) {
        float bval = bias[ct * 16 + l16];
        for (int rt = 0; rt < 2; ++rt) {
            for (int reg = 0; reg < 4; ++reg) {
                float x = acc[ct][rt][reg] + bval;
                float t  = 0.7978845608028654f * (x + 0.044715f * x * x * x);
                float th = 1.0f - 2.0f / (__expf(2.0f * t) + 1.0f);
                float g  = 0.5f * x * (1.0f + th);
                xs[(wrow + rt * 16 + quad * 4 + reg) * LDST + ct * 16 + l16] = (_Float16)g;
            }
        }
    }
    __syncthreads();

    unsigned char* Y = (which == 0) ? q8i : (which == 1) ? k8i : v8i;
    // int8 per-row quant. In each it, the 16-lane group (flat&15) covers the
    // FULL 128-dim row r -> row-max via 4 shfl_xor steps (16-aligned groups).
    for (int it = 0; it < 8; ++it) {
        int flat = it * 256 + tid;
        int r  = flat >> 4;
        int c8 = (flat & 15) * 8;
        int gr = rowblock + r;
        f16x8 h = *(const f16x8*)(&xs[r * LDST + c8]);
        float f[8];
        float mx = 0.0f;
#pragma unroll
        for (int j = 0; j < 8; ++j) {
            f[j] = (float)h[j];
            mx = fmaxf(mx, fabsf(f[j]));
        }
        mx = fmaxf(mx, __shfl_xor(mx, 1));
        mx = fmaxf(mx, __shfl_xor(mx, 2));
        mx = fmaxf(mx, __shfl_xor(mx, 4));
        mx = fmaxf(mx, __shfl_xor(mx, 8));
        float qs = (mx > 0.0f) ? 127.0f / mx : 0.0f;
        if (gr < R) {
            unsigned int w0 = 0, w1 = 0;
#pragma unroll
            for (int j = 0; j < 4; ++j) {
                int q = (int)rintf(fminf(fmaxf(f[j] * qs, -127.0f), 127.0f));
                w0 |= ((unsigned int)(q & 0xff)) << (8 * j);
            }
#pragma unroll
            for (int j = 0; j < 4; ++j) {
                int q = (int)rintf(fminf(fmaxf(f[4 + j] * qs, -127.0f), 127.0f));
                w1 |= ((unsigned int)(q & 0xff)) << (8 * j);
            }
            *(uint2*)(Y + (size_t)gr * DIM + c8) = make_uint2(w0, w1);
            if ((flat & 15) == 0) {
                float ds = mx * (1.0f / 127.0f);
                if (which == 0)      sclq[gr]   = ds;
                else if (which == 1) scl2[gr].x = ds;
                else                 scl2[gr].y = ds;
            }
        }
    }
}

// ---------------------------------------------------------------------------
// Kernel 3: per-row edge attention. One wave per row; RESTRUCTURED this
// round to 8 lanes/edge x 16B/lane (was 16 lanes x 8B):
//  - 2 dwordx4 gathers per 8-edge iteration (was 4) -> half the address
//    math and vmem issues
//  - score dot: 4x v_dot4_i32_i8 on int8 q/k (was 6-inst fp8 unpack-dots);
//    int shuffle reduce is 3 steps for all 8 edges at once (was 8 shfls)
//  - per-iteration VALU ~halved vs R5; lines/edge stays 2 (k=1, v=1)
// lane decomposition: g = lane>>3 (edge slot 0-7), d8 = lane&7 (dims
// [d8*16, d8*16+16)). Final merge across g via shfl_xor 8/16/32.
// ---------------------------------------------------------------------------
__global__ __launch_bounds__(256) void edge_attn_kernel(
    const unsigned char* __restrict__ q8i, const float* __restrict__ sclq,
    const unsigned char* __restrict__ k8i, const unsigned char* __restrict__ v8i,
    const float2* __restrict__ scl2, const float* __restrict__ adj_vals,
    const int* __restrict__ cols, const int* __restrict__ row_ptr,
    float* __restrict__ out, int n)
{
    int row = blockIdx.x * 4 + (threadIdx.x >> 6);
    if (row >= n) return;
    int lane = threadIdx.x & 63;
    int g    = lane >> 3;    // edge slot
    int d8   = lane & 7;     // dim slot: dims [d8*16, d8*16+16)

    int start = row_ptr[row];
    int end   = row_ptr[row + 1];

    int4  qw = *(const int4*)(q8i + (size_t)row * DIM + d8 * 16);
    float sq = sclq[row];

    float s_sum = 0.0f;
    float acc[16];
#pragma unroll
    for (int j = 0; j < 16; ++j) acc[j] = 0.0f;

    const float scale = 0.08838834764831845f;   // 1/sqrt(128)

    for (int gg = start; gg < end; gg += 8) {
        int e     = gg + g;
        bool vld  = e < end;
        int  i    = vld ? e : end - 1;
        int  c    = cols[i];
        float a   = adj_vals[i] * scale;
        float2 sk = scl2[c];

        const unsigned char* base = k8i + (size_t)c * DIM + d8 * 16;
        int4 kw = *(const int4*)base;
        int4 vw = *(const int4*)(v8i + (size_t)c * DIM + d8 * 16);

        int di = dot4i8(qw.x, kw.x, 0);
        di = dot4i8(qw.y, kw.y, di);
        di = dot4i8(qw.z, kw.z, di);
        di = dot4i8(qw.w, kw.w, di);
        di += __shfl_xor(di, 1);
        di += __shfl_xor(di, 2);
        di += __shfl_xor(di, 4);

        float score = (float)di * (sq * sk.x) * a;
        float p = vld ? __expf(score) : 0.0f;
        s_sum += p;

        float psv = p * sk.y;   // fold v dequant scale into weight
#pragma unroll
        for (int j = 0; j < 4; ++j) {
            acc[j]      += psv * i8f((unsigned int)vw.x, j);
            acc[4 + j]  += psv * i8f((unsigned int)vw.y, j);
            acc[8 + j]  += psv * i8f((unsigned int)vw.z, j);
            acc[12 + j] += psv * i8f((unsigned int)vw.w, j);
        }
    }

    // merge the 8 edge slots (lane bits 3..5)
    s_sum += __shfl_xor(s_sum, 8);
    s_sum += __shfl_xor(s_sum, 16);
    s_sum += __shfl_xor(s_sum, 32);
#pragma unroll
    for (int j = 0; j < 16; ++j) {
        acc[j] += __shfl_xor(acc[j], 8);
        acc[j] += __shfl_xor(acc[j], 16);
        acc[j] += __shfl_xor(acc[j], 32);
    }
    float inv = (s_sum > 0.0f) ? 1.0f / s_sum : 0.0f;   // empty row -> zeros

    if (g == 0) {
        float4* dst = (float4*)(out + (size_t)row * DIM + d8 * 16);
#pragma unroll
        for (int j = 0; j < 4; ++j)
            dst[j] = make_float4(acc[4 * j] * inv, acc[4 * j + 1] * inv,
                                 acc[4 * j + 2] * inv, acc[4 * j + 3] * inv);
    }
}

// ---------------------------------------------------------------------------
extern "C" void kernel_launch(void* const* d_in, const int* in_sizes, int n_in,
                              void* d_out, int out_size, void* d_ws, size_t ws_size,
                              hipStream_t stream)
{
    const float* query    = (const float*)d_in[0];
    const float* memory   = (const float*)d_in[1];
    const float* adj_vals = (const float*)d_in[2];
    const float* Wq       = (const float*)d_in[3];
    const float* bq       = (const float*)d_in[4];
    const float* Wk       = (const float*)d_in[5];
    const float* bk       = (const float*)d_in[6];
    const float* Wv       = (const float*)d_in[7];
    const float* bv       = (const float*)d_in[8];
    const int*   rows     = (const int*)d_in[9];
    const int*   cols     = (const int*)d_in[10];
    float* out = (float*)d_out;

    int n = in_sizes[0] / DIM;   // 50000
    int m = in_sizes[1] / DIM;   // 50000
    int e = in_sizes[9];         // 1600000

    // workspace layout (16B-aligned)
    char* ws = (char*)d_ws;
    size_t off = 0;
    _Float16* Wt = (_Float16*)(ws + off);       off += (size_t)3 * DIM * DIM * 2; // 98KB
    unsigned char* q8i = (unsigned char*)(ws + off); off += (size_t)n * DIM;      // 6.4MB
    unsigned char* k8i = (unsigned char*)(ws + off); off += (size_t)m * DIM;      // 6.4MB
    unsigned char* v8i = (unsigned char*)(ws + off); off += (size_t)m * DIM;      // 6.4MB
    float* sclq  = (float*)(ws + off);          off += (size_t)n * 4;             // 200KB
    float2* scl2 = (float2*)(ws + off);         off += (size_t)m * 8;             // 400KB
    int* row_ptr = (int*)(ws + off);            off += (size_t)(n + 1) * 4;

    int rp_blocks = (n + 1 + 255) / 256;
    setup_kernel<<<dim3(192 + rp_blocks), 256, 0, stream>>>(
        Wq, Wk, Wv, Wt, rows, row_ptr, n, e);

    proj_gemm_kernel<<<dim3((n + 127) / 128, 3), 256, 0, stream>>>(
        query, memory, Wt, bq, bk, bv, q8i, sclq, k8i, v8i, scl2, n, m);

    edge_attn_kernel<<<dim3((n + 3) / 4), 256, 0, stream>>>(
        q8i, sclq, k8i, v8i, scl2, adj_vals, cols, row_ptr, out, n);
}

// Round 7
// 217.637 us; speedup vs baseline: 1.2058x; 1.0172x over previous
//
#include <hip/hip_runtime.h>
#include <math.h>

typedef _Float16 f16x2 __attribute__((ext_vector_type(2)));
typedef _Float16 f16x4 __attribute__((ext_vector_type(4)));
typedef _Float16 f16x8 __attribute__((ext_vector_type(8)));
typedef float f32x4 __attribute__((ext_vector_type(4)));

#define DIM 128
#define LDST 136   // padded LDS row stride in f16 elems (272B, 16B-aligned)
#define KVR 256    // interleaved record: k int8 [0,128) | v biased-uint8 [128,256)

#if defined(__has_builtin)
#if __has_builtin(__builtin_amdgcn_sdot4)
#define HAVE_SDOT4 1
#endif
#if __has_builtin(__builtin_amdgcn_perm)
#define HAVE_PERM 1
#endif
#if __has_builtin(__builtin_amdgcn_exp2f)
#define HAVE_EXP2 1
#endif
#endif

__device__ __forceinline__ float fast_exp2(float x) {
#ifdef HAVE_EXP2
    return __builtin_amdgcn_exp2f(x);
#else
    return exp2f(x);
#endif
}

// 4-byte int8 dot product: d += dot(a.4xi8, b.4xi8)
__device__ __forceinline__ int dot4i8(int a, int b, int c) {
#ifdef HAVE_SDOT4
    return __builtin_amdgcn_sdot4(a, b, c, false);
#else
    int s = c;
#pragma unroll
    for (int j = 0; j < 4; ++j)
        s += (int)((signed char)((a >> (8 * j)) & 0xff)) *
             (int)((signed char)((b >> (8 * j)) & 0xff));
    return s;
#endif
}

union U32H2 { unsigned int u; f16x2 h; };

// biased-uint8 pair -> f16 pair (1024+b0, 1024+b1) via one v_perm_b32.
// f16 bit pattern 0x6400|b == 1024+b exactly for b in [0,255].
__device__ __forceinline__ f16x2 byte2f16(unsigned int w, unsigned int sel) {
    U32H2 u;
#ifdef HAVE_PERM
    u.u = __builtin_amdgcn_perm(0x64646464u, w, sel);
#else
    unsigned b0 = (w >> (8 * (sel & 3))) & 0xff;
    unsigned b1 = (w >> (8 * ((sel >> 16) & 3))) & 0xff;
    u.u = 0x64006400u | b0 | (b1 << 16);
#endif
    return u.h;
}

// ---------------------------------------------------------------------------
// Kernel 1: setup — fused weight transpose/f16-convert + CSR row_ptr build.
// ---------------------------------------------------------------------------
__global__ __launch_bounds__(256) void setup_kernel(
    const float* __restrict__ Wq, const float* __restrict__ Wk,
    const float* __restrict__ Wv, _Float16* __restrict__ Wt,
    const int* __restrict__ rows, int* __restrict__ row_ptr, int n, int e)
{
    int b = blockIdx.x;
    if (b < 192) {
        int mat = b >> 6;
        const float* W = (mat == 0) ? Wq : (mat == 1) ? Wk : Wv;
        _Float16* dst = Wt + (size_t)mat * DIM * DIM;
        int idx = (b & 63) * 256 + threadIdx.x;
        int k = idx >> 7;
        int c = idx & 127;
        dst[c * DIM + k] = (_Float16)W[idx];
    } else {
        int r = (b - 192) * 256 + threadIdx.x;
        if (r > n) return;
        if (r == n) { row_ptr[n] = e; return; }
        int lo = 0, hi = e;
        while (lo < hi) {
            int mid = (lo + hi) >> 1;
            if (rows[mid] < r) lo = mid + 1; else hi = mid;
        }
        row_ptr[r] = lo;
    }
}

// ---------------------------------------------------------------------------
// Kernel 2: fused projection GEMM  Y = gelu(X @ W + b), int8 per-row scale.
//   which==0 -> q8i (signed int8) + sclq
//   which==1 -> kv record bytes [0,128)  (signed int8 k) + scl2[].x
//   which==2 -> kv record bytes [128,256) (BIASED uint8 v = q+128) + scl2[].y
// The bias enables the edge kernel's 0x6400|b f16 unpack trick; the
// constant folds out via spsv there.
// ---------------------------------------------------------------------------
__global__ __launch_bounds__(256, 3) void proj_gemm_kernel(
    const float* __restrict__ query, const float* __restrict__ memory,
    const _Float16* __restrict__ Wt,
    const float* __restrict__ bq, const float* __restrict__ bk,
    const float* __restrict__ bv,
    unsigned char* __restrict__ q8i, float* __restrict__ sclq,
    unsigned char* __restrict__ kv, float2* __restrict__ scl2,
    int n, int m)
{
    __shared__ _Float16 xs[128 * LDST];   // 34816 B

    int which = blockIdx.y;
    const float* X     = (which == 0) ? query : memory;
    const _Float16* Wm = Wt + (size_t)which * DIM * DIM;
    const float* bias  = (which == 0) ? bq : (which == 1) ? bk : bv;
    int R              = (which == 0) ? n : m;

    int tid = threadIdx.x;
    int rowblock = blockIdx.x * 128;
    if (rowblock >= R) return;

    for (int it = 0; it < 16; ++it) {
        int flat = it * 256 + tid;
        int r  = flat >> 5;
        int c4 = (flat & 31) * 4;
        int gr = rowblock + r;
        if (gr >= R) gr = R - 1;
        float4 x = *(const float4*)(X + (size_t)gr * DIM + c4);
        f16x4 w4;
        w4[0] = (_Float16)x.x; w4[1] = (_Float16)x.y;
        w4[2] = (_Float16)x.z; w4[3] = (_Float16)x.w;
        *(f16x4*)(&xs[r * LDST + c4]) = w4;
    }
    __syncthreads();

    int wave = tid >> 6;
    int lane = tid & 63;
    int quad = lane >> 4;
    int l16  = lane & 15;
    int wrow = wave * 32;

    f16x8 afrag[2][4];
    for (int rt = 0; rt < 2; ++rt)
        for (int ks = 0; ks < 4; ++ks)
            afrag[rt][ks] = *(const f16x8*)(&xs[(wrow + rt * 16 + l16) * LDST + quad * 8 + ks * 32]);

    f32x4 acc[8][2];
    for (int ct = 0; ct < 8; ++ct) { acc[ct][0] = {0,0,0,0}; acc[ct][1] = {0,0,0,0}; }
    for (int ct = 0; ct < 8; ++ct) {
        const _Float16* wp = Wm + (size_t)(ct * 16 + l16) * DIM + quad * 8;
        for (int ks = 0; ks < 4; ++ks) {
            f16x8 b = *(const f16x8*)(wp + ks * 32);
            acc[ct][0] = __builtin_amdgcn_mfma_f32_16x16x32_f16(afrag[0][ks], b, acc[ct][0], 0, 0, 0);
            acc[ct][1] = __builtin_amdgcn_mfma_f32_16x16x32_f16(afrag[1][ks], b, acc[ct][1], 0, 0, 0);
        }
    }

    __syncthreads();
    for (int ct = 0; ct < 8; ++ct) {
        float bval = bias[ct * 16 + l16];
        for (int rt = 0; rt < 2; ++rt) {
            for (int reg = 0; reg < 4; ++reg) {
                float x = acc[ct][rt][reg] + bval;
                float t  = 0.7978845608028654f * (x + 0.044715f * x * x * x);
                float th = 1.0f - 2.0f / (__expf(2.0f * t) + 1.0f);
                float g  = 0.5f * x * (1.0f + th);
                xs[(wrow + rt * 16 + quad * 4 + reg) * LDST + ct * 16 + l16] = (_Float16)g;
            }
        }
    }
    __syncthreads();

    int qbias = (which == 2) ? 128 : 0;
    // int8 per-row quant. In each it, the 16-lane group (flat&15) covers the
    // FULL 128-dim row r -> row-max via 4 shfl_xor steps (16-aligned groups).
    for (int it = 0; it < 8; ++it) {
        int flat = it * 256 + tid;
        int r  = flat >> 4;
        int c8 = (flat & 15) * 8;
        int gr = rowblock + r;
        f16x8 h = *(const f16x8*)(&xs[r * LDST + c8]);
        float f[8];
        float mx = 0.0f;
#pragma unroll
        for (int j = 0; j < 8; ++j) {
            f[j] = (float)h[j];
            mx = fmaxf(mx, fabsf(f[j]));
        }
        mx = fmaxf(mx, __shfl_xor(mx, 1));
        mx = fmaxf(mx, __shfl_xor(mx, 2));
        mx = fmaxf(mx, __shfl_xor(mx, 4));
        mx = fmaxf(mx, __shfl_xor(mx, 8));
        float qs = (mx > 0.0f) ? 127.0f / mx : 0.0f;
        if (gr < R) {
            unsigned int w0 = 0, w1 = 0;
#pragma unroll
            for (int j = 0; j < 4; ++j) {
                int q = (int)rintf(fminf(fmaxf(f[j] * qs, -127.0f), 127.0f)) + qbias;
                w0 |= ((unsigned int)(q & 0xff)) << (8 * j);
            }
#pragma unroll
            for (int j = 0; j < 4; ++j) {
                int q = (int)rintf(fminf(fmaxf(f[4 + j] * qs, -127.0f), 127.0f)) + qbias;
                w1 |= ((unsigned int)(q & 0xff)) << (8 * j);
            }
            if (which == 0)
                *(uint2*)(q8i + (size_t)gr * DIM + c8) = make_uint2(w0, w1);
            else if (which == 1)
                *(uint2*)(kv + (size_t)gr * KVR + c8) = make_uint2(w0, w1);
            else
                *(uint2*)(kv + (size_t)gr * KVR + 128 + c8) = make_uint2(w0, w1);
            if ((flat & 15) == 0) {
                float ds = mx * (1.0f / 127.0f);
                if (which == 0)      sclq[gr]   = ds;
                else if (which == 1) scl2[gr].x = ds;
                else                 scl2[gr].y = ds;
            }
        }
    }
}

// ---------------------------------------------------------------------------
// Kernel 3: per-row edge attention. 8 lanes/edge x 16B/lane. R7 changes:
//  - interleaved kv record: ONE gather base per edge, v at imm offset:128
//  - PV: byte->f16 via v_perm magic-bias + v_fma_mix_f32 (f32 accumulate):
//    24 insts per 16 dims (was 48 bfe+cvt+fma). Bias 1152 folds out via
//    spsv (acc[j] -= 1152*spsv after the loop).
//  - exp2 with log2e folded into the row-constant scale.
// ---------------------------------------------------------------------------
__global__ __launch_bounds__(256) void edge_attn_kernel(
    const unsigned char* __restrict__ q8i, const float* __restrict__ sclq,
    const unsigned char* __restrict__ kv, const float2* __restrict__ scl2,
    const float* __restrict__ adj_vals, const int* __restrict__ cols,
    const int* __restrict__ row_ptr, float* __restrict__ out, int n)
{
    int row = blockIdx.x * 4 + (threadIdx.x >> 6);
    if (row >= n) return;
    int lane = threadIdx.x & 63;
    int g    = lane >> 3;    // edge slot
    int d8   = lane & 7;     // dim slot: dims [d8*16, d8*16+16)

    int start = row_ptr[row];
    int end   = row_ptr[row + 1];

    int4  qw = *(const int4*)(q8i + (size_t)row * DIM + d8 * 16);
    // row-constant: sq * 1/sqrt(128) * log2(e)
    float csr = sclq[row] * (0.08838834764831845f * 1.442695040888963f);

    float s_sum = 0.0f;
    float spsv  = 0.0f;
    float acc[16];
#pragma unroll
    for (int j = 0; j < 16; ++j) acc[j] = 0.0f;

    for (int gg = start; gg < end; gg += 8) {
        int e     = gg + g;
        bool vld  = e < end;
        int  i    = vld ? e : end - 1;
        int  c    = cols[i];
        float a   = adj_vals[i];
        float2 sk = scl2[c];

        const unsigned char* base = kv + (size_t)c * KVR + d8 * 16;
        int4 kw = *(const int4*)base;
        int4 vw = *(const int4*)(base + 128);

        int di = dot4i8(qw.x, kw.x, 0);
        di = dot4i8(qw.y, kw.y, di);
        di = dot4i8(qw.z, kw.z, di);
        di = dot4i8(qw.w, kw.w, di);
        di += __shfl_xor(di, 1);
        di += __shfl_xor(di, 2);
        di += __shfl_xor(di, 4);

        float p = vld ? fast_exp2((float)di * (csr * sk.x * a)) : 0.0f;
        s_sum += p;

        float psv = p * sk.y;   // fold v dequant scale into weight
        spsv += psv;
#pragma unroll
        for (int d = 0; d < 4; ++d) {
            unsigned int w = (d == 0) ? (unsigned int)vw.x : (d == 1) ? (unsigned int)vw.y
                           : (d == 2) ? (unsigned int)vw.z : (unsigned int)vw.w;
            f16x2 lo = byte2f16(w, 0x04010400u);   // (1024+b0, 1024+b1)
            f16x2 hi = byte2f16(w, 0x04030402u);   // (1024+b2, 1024+b3)
            acc[4 * d]     += psv * (float)lo[0];  // v_fma_mix_f32
            acc[4 * d + 1] += psv * (float)lo[1];
            acc[4 * d + 2] += psv * (float)hi[0];
            acc[4 * d + 3] += psv * (float)hi[1];
        }
    }

    // remove the 1024+128 unpack bias: each raw = 1152 + q
#pragma unroll
    for (int j = 0; j < 16; ++j) acc[j] -= 1152.0f * spsv;

    // merge the 8 edge slots (lane bits 3..5)
    s_sum += __shfl_xor(s_sum, 8);
    s_sum += __shfl_xor(s_sum, 16);
    s_sum += __shfl_xor(s_sum, 32);
#pragma unroll
    for (int j = 0; j < 16; ++j) {
        acc[j] += __shfl_xor(acc[j], 8);
        acc[j] += __shfl_xor(acc[j], 16);
        acc[j] += __shfl_xor(acc[j], 32);
    }
    float inv = (s_sum > 0.0f) ? 1.0f / s_sum : 0.0f;   // empty row -> zeros

    if (g == 0) {
        float4* dst = (float4*)(out + (size_t)row * DIM + d8 * 16);
#pragma unroll
        for (int j = 0; j < 4; ++j)
            dst[j] = make_float4(acc[4 * j] * inv, acc[4 * j + 1] * inv,
                                 acc[4 * j + 2] * inv, acc[4 * j + 3] * inv);
    }
}

// ---------------------------------------------------------------------------
extern "C" void kernel_launch(void* const* d_in, const int* in_sizes, int n_in,
                              void* d_out, int out_size, void* d_ws, size_t ws_size,
                              hipStream_t stream)
{
    const float* query    = (const float*)d_in[0];
    const float* memory   = (const float*)d_in[1];
    const float* adj_vals = (const float*)d_in[2];
    const float* Wq       = (const float*)d_in[3];
    const float* bq       = (const float*)d_in[4];
    const float* Wk       = (const float*)d_in[5];
    const float* bk       = (const float*)d_in[6];
    const float* Wv       = (const float*)d_in[7];
    const float* bv       = (const float*)d_in[8];
    const int*   rows     = (const int*)d_in[9];
    const int*   cols     = (const int*)d_in[10];
    float* out = (float*)d_out;

    int n = in_sizes[0] / DIM;   // 50000
    int m = in_sizes[1] / DIM;   // 50000
    int e = in_sizes[9];         // 1600000

    // workspace layout (16B-aligned)
    char* ws = (char*)d_ws;
    size_t off = 0;
    _Float16* Wt = (_Float16*)(ws + off);            off += (size_t)3 * DIM * DIM * 2; // 98KB
    unsigned char* q8i = (unsigned char*)(ws + off); off += (size_t)n * DIM;           // 6.4MB
    unsigned char* kv  = (unsigned char*)(ws + off); off += (size_t)m * KVR;           // 12.8MB
    float* sclq  = (float*)(ws + off);               off += (size_t)n * 4;             // 200KB
    float2* scl2 = (float2*)(ws + off);              off += (size_t)m * 8;             // 400KB
    int* row_ptr = (int*)(ws + off);                 off += (size_t)(n + 1) * 4;

    int rp_blocks = (n + 1 + 255) / 256;
    setup_kernel<<<dim3(192 + rp_blocks), 256, 0, stream>>>(
        Wq, Wk, Wv, Wt, rows, row_ptr, n, e);

    proj_gemm_kernel<<<dim3((n + 127) / 128, 3), 256, 0, stream>>>(
        query, memory, Wt, bq, bk, bv, q8i, sclq, kv, scl2, n, m);

    edge_attn_kernel<<<dim3((n + 3) / 4), 256, 0, stream>>>(
        q8i, sclq, kv, scl2, adj_vals, cols, row_ptr, out, n);
}